// Round 1
// baseline (2899.862 us; speedup 1.0000x reference)
//
#include <hip/hip_runtime.h>

typedef float f32x4 __attribute__((ext_vector_type(4)));
typedef short short8 __attribute__((ext_vector_type(8)));

#define T_LEN 2048
#define NB 8
#define HD 256
#define SD 64
#define DIN 768
#define DOUT 768
#define MROWS 16384  // B*T

__device__ __forceinline__ unsigned short f2bf(float f) {
    unsigned int u = __float_as_uint(f);
    unsigned int r = u + 0x7FFFu + ((u >> 16) & 1u);
    return (unsigned short)(r >> 16);
}
__device__ __forceinline__ float bf2f(unsigned short h) {
    return __uint_as_float(((unsigned int)h) << 16);
}

// ---------------- conversions ----------------
__global__ __launch_bounds__(256) void cvt_x_k(const float* __restrict__ s,
                                               unsigned short* __restrict__ d, int n4) {
    int i = blockIdx.x * 256 + threadIdx.x;
    if (i >= n4) return;
    float4 v = reinterpret_cast<const float4*>(s)[i];
    ushort4 o;
    o.x = f2bf(v.x); o.y = f2bf(v.y); o.z = f2bf(v.z); o.w = f2bf(v.w);
    reinterpret_cast<ushort4*>(d)[i] = o;
}

// weights concatenated bf16: [inw 196608][ipw 65536][gw 262144][pw 262144][cw 65536][ow 196608]
__global__ __launch_bounds__(256) void cvt_w_k(const float* __restrict__ s0, const float* __restrict__ s1,
                                               const float* __restrict__ s2, const float* __restrict__ s3,
                                               const float* __restrict__ s4, const float* __restrict__ s5,
                                               unsigned short* __restrict__ d) {
    int i = blockIdx.x * 256 + threadIdx.x;
    if (i >= 1048576) return;
    float v;
    if (i < 196608)      v = s0[i];
    else if (i < 262144) v = s1[i - 196608];
    else if (i < 524288) v = s2[i - 262144];
    else if (i < 786432) v = s3[i - 524288];
    else if (i < 851968) v = s4[i - 786432];
    else                 v = s5[i - 851968];
    d[i] = f2bf(v);
}

// ---------------- LayerNorm: h fp32 -> xn bf16 ----------------
__global__ __launch_bounds__(256) void ln_k(const float* __restrict__ h, const float* __restrict__ g,
                                            const float* __restrict__ be, unsigned short* __restrict__ xnb) {
    int row = blockIdx.x * 4 + (threadIdx.x >> 6);
    int l = threadIdx.x & 63;
    const float4 x = *reinterpret_cast<const float4*>(h + row * HD + l * 4);
    float s = x.x + x.y + x.z + x.w;
    float s2 = x.x * x.x + x.y * x.y + x.z * x.z + x.w * x.w;
#pragma unroll
    for (int m = 1; m < 64; m <<= 1) { s += __shfl_xor(s, m); s2 += __shfl_xor(s2, m); }
    float mean = s * (1.f / 256.f);
    float var = s2 * (1.f / 256.f) - mean * mean;
    float rstd = rsqrtf(var + 1e-5f);
    int c = l * 4;
    ushort4 o;
    o.x = f2bf((x.x - mean) * rstd * g[c + 0] + be[c + 0]);
    o.y = f2bf((x.y - mean) * rstd * g[c + 1] + be[c + 1]);
    o.z = f2bf((x.z - mean) * rstd * g[c + 2] + be[c + 2]);
    o.w = f2bf((x.w - mean) * rstd * g[c + 3] + be[c + 3]);
    *reinterpret_cast<ushort4*>(xnb + row * HD + l * 4) = o;
}

// ---------------- GEMM: out = A[M,K](bf16) @ W[N,K]^T (bf16) + bias, epilogue by MODE --------
// MODE 0: outf[m*N+n] = v                        (fp32 out)
// MODE 1: u = aux0[n]*v + aux1[n]; outf[((t*8)+b)*64+n], m=b*2048+t   (x_state->u, N=64)
// MODE 2: outb[m*N+n] = bf16(sigmoid(v))         (gate)
// MODE 3: outb[m*N+n] = bf16(v)                  (y from scan states)
// MODE 4: rows m=(t*8+b); r=b*2048+t; hn = h[r,n] + g*v + (1-g)*xn; outf=h upd, outb=h bf16
template <int K, int N, int MODE>
__global__ __launch_bounds__(256) void gemm_k(const unsigned short* __restrict__ A,
                                              const unsigned short* __restrict__ W,
                                              const float* __restrict__ bias,
                                              float* __restrict__ outf, unsigned short* __restrict__ outb,
                                              const float* __restrict__ aux0, const float* __restrict__ aux1,
                                              const unsigned short* __restrict__ gb,
                                              const unsigned short* __restrict__ xnb) {
    const int l = threadIdx.x & 63, w = threadIdx.x >> 6;
    const int ll = l & 15, lh = l >> 4;
    const int m0 = blockIdx.x * 128 + w * 32;
    const int n0 = blockIdx.y * 64;
    f32x4 acc[2][4] = {};
    const unsigned short* Ap = A + (size_t)(m0 + ll) * K + lh * 8;
    const unsigned short* Wp = W + (size_t)(n0 + ll) * K + lh * 8;
#pragma unroll
    for (int k0 = 0; k0 < K; k0 += 32) {
        short8 a0 = *reinterpret_cast<const short8*>(Ap + k0);
        short8 a1 = *reinterpret_cast<const short8*>(Ap + 16 * K + k0);
        short8 b0 = *reinterpret_cast<const short8*>(Wp + k0);
        short8 b1 = *reinterpret_cast<const short8*>(Wp + 16 * K + k0);
        short8 b2 = *reinterpret_cast<const short8*>(Wp + 32 * K + k0);
        short8 b3 = *reinterpret_cast<const short8*>(Wp + 48 * K + k0);
        acc[0][0] = __builtin_amdgcn_mfma_f32_16x16x32_bf16(a0, b0, acc[0][0], 0, 0, 0);
        acc[0][1] = __builtin_amdgcn_mfma_f32_16x16x32_bf16(a0, b1, acc[0][1], 0, 0, 0);
        acc[0][2] = __builtin_amdgcn_mfma_f32_16x16x32_bf16(a0, b2, acc[0][2], 0, 0, 0);
        acc[0][3] = __builtin_amdgcn_mfma_f32_16x16x32_bf16(a0, b3, acc[0][3], 0, 0, 0);
        acc[1][0] = __builtin_amdgcn_mfma_f32_16x16x32_bf16(a1, b0, acc[1][0], 0, 0, 0);
        acc[1][1] = __builtin_amdgcn_mfma_f32_16x16x32_bf16(a1, b1, acc[1][1], 0, 0, 0);
        acc[1][2] = __builtin_amdgcn_mfma_f32_16x16x32_bf16(a1, b2, acc[1][2], 0, 0, 0);
        acc[1][3] = __builtin_amdgcn_mfma_f32_16x16x32_bf16(a1, b3, acc[1][3], 0, 0, 0);
    }
#pragma unroll
    for (int mf = 0; mf < 2; mf++)
#pragma unroll
        for (int nf = 0; nf < 4; nf++)
#pragma unroll
            for (int r = 0; r < 4; r++) {
                int m = m0 + mf * 16 + lh * 4 + r;
                int n = n0 + nf * 16 + ll;
                float v = acc[mf][nf][r] + bias[n];
                if constexpr (MODE == 0) {
                    outf[(size_t)m * N + n] = v;
                } else if constexpr (MODE == 1) {
                    float uu = aux0[n] * v + aux1[n];
                    int t = m & 2047, b = m >> 11;
                    outf[((t << 3) + b) * 64 + n] = uu;
                } else if constexpr (MODE == 2) {
                    float gg = 1.f / (1.f + __expf(-v));
                    outb[(size_t)m * N + n] = f2bf(gg);
                } else if constexpr (MODE == 3) {
                    outb[(size_t)m * N + n] = f2bf(v);
                } else if constexpr (MODE == 4) {
                    int t = m >> 3, b = m & 7;
                    int idx = ((b << 11) + t) * HD + n;
                    float g = bf2f(gb[idx]);
                    float xv = bf2f(xnb[idx]);
                    float hn = outf[idx] + g * v + (1.f - g) * xv;
                    outf[idx] = hn;
                    outb[idx] = f2bf(hn);
                }
            }
}

// ---------------- sequential scan (fp32 exact, with clip) ----------------
// one wave per batch; lane s holds h[s]; A-row in registers; readlane broadcast
__global__ __launch_bounds__(64) void scan_k(const float* __restrict__ Af,
                                             const float* __restrict__ u,
                                             unsigned short* __restrict__ Hs) {
    const int b = blockIdx.x;
    const int s = threadIdx.x;
    float a[64];
#pragma unroll
    for (int q = 0; q < 16; q++) {
        float4 v = reinterpret_cast<const float4*>(Af + s * 64)[q];
        a[q * 4 + 0] = v.x; a[q * 4 + 1] = v.y; a[q * 4 + 2] = v.z; a[q * 4 + 3] = v.w;
    }
    float h = 0.f;
    for (int t = 0; t < T_LEN; t++) {
        float uu = u[((t << 3) + b) * 64 + s];
        float ac0 = uu, ac1 = 0.f, ac2 = 0.f, ac3 = 0.f;
#pragma unroll
        for (int k = 0; k < 64; k += 4) {
            float b0 = __int_as_float(__builtin_amdgcn_readlane(__float_as_int(h), k + 0));
            float b1 = __int_as_float(__builtin_amdgcn_readlane(__float_as_int(h), k + 1));
            float b2 = __int_as_float(__builtin_amdgcn_readlane(__float_as_int(h), k + 2));
            float b3 = __int_as_float(__builtin_amdgcn_readlane(__float_as_int(h), k + 3));
            ac0 = fmaf(b0, a[k + 0], ac0);
            ac1 = fmaf(b1, a[k + 1], ac1);
            ac2 = fmaf(b2, a[k + 2], ac2);
            ac3 = fmaf(b3, a[k + 3], ac3);
        }
        float hp = (ac0 + ac1) + (ac2 + ac3);
        h = fminf(fmaxf(hp, -10.f), 10.f);
        Hs[((t << 3) + b) * 64 + s] = f2bf(h);
    }
}

// ---------------- launch ----------------
extern "C" void kernel_launch(void* const* d_in, const int* in_sizes, int n_in,
                              void* d_out, int out_size, void* d_ws, size_t ws_size,
                              hipStream_t stream) {
    const float* x    = (const float*)d_in[0];
    const float* inw  = (const float*)d_in[1];
    const float* inb  = (const float*)d_in[2];
    const float* lng  = (const float*)d_in[3];
    const float* lnb  = (const float*)d_in[4];
    const float* ipw  = (const float*)d_in[5];
    const float* ipb  = (const float*)d_in[6];
    const float* Amat = (const float*)d_in[7];
    const float* Bv   = (const float*)d_in[8];
    const float* Cm   = (const float*)d_in[9];
    const float* bA   = (const float*)d_in[10];
    const float* bC   = (const float*)d_in[11];
    const float* gw   = (const float*)d_in[12];
    const float* gbia = (const float*)d_in[13];
    const float* pw   = (const float*)d_in[14];
    const float* pb   = (const float*)d_in[15];
    const float* ow   = (const float*)d_in[16];
    const float* ob   = (const float*)d_in[17];

    char* ws = (char*)d_ws;
    // region 0: xb (25165824 B) reused later for u/Hs/yb/hb
    unsigned short* xb = (unsigned short*)(ws + 0);
    float*          u  = (float*)(ws + 0);
    unsigned short* Hs = (unsigned short*)(ws + 4194304);
    unsigned short* yb = (unsigned short*)(ws + 6291456);
    unsigned short* hb = (unsigned short*)(ws + 14680064);
    unsigned short* wb = (unsigned short*)(ws + 25165824);  // 2097152 B
    float*          h  = (float*)(ws + 27262976);           // 16777216 B
    unsigned short* xnb = (unsigned short*)(ws + 44040192); // 8388608 B
    unsigned short* gB  = (unsigned short*)(ws + 52428800); // 8388608 B

    const unsigned short* w_in = wb + 0;
    const unsigned short* w_ip = wb + 196608;
    const unsigned short* w_g  = wb + 262144;
    const unsigned short* w_p  = wb + 524288;
    const unsigned short* w_c  = wb + 786432;
    const unsigned short* w_o  = wb + 851968;

    cvt_x_k<<<12288, 256, 0, stream>>>(x, xb, 3145728);
    cvt_w_k<<<4096, 256, 0, stream>>>(inw, ipw, gw, pw, Cm, ow, wb);

    // h = x @ in_proj_w^T + b
    gemm_k<DIN, HD, 0><<<dim3(128, 4), 256, 0, stream>>>(xb, w_in, inb, h, nullptr,
                                                         nullptr, nullptr, nullptr, nullptr);
    for (int i = 0; i < 4; i++) {
        ln_k<<<4096, 256, 0, stream>>>(h, lng + i * HD, lnb + i * HD, xnb);
        // u = Bv*(xn@ip_w^T + ip_b) + bias_A  -> [t][b][s]
        gemm_k<HD, SD, 1><<<dim3(128, 1), 256, 0, stream>>>(xnb, w_ip + i * 16384, ipb + i * SD,
                                                            u, nullptr, Bv + i * SD, bA + i * SD,
                                                            nullptr, nullptr);
        // gate = sigmoid(xn@gate_w^T + gate_b) (bf16)
        gemm_k<HD, HD, 2><<<dim3(128, 4), 256, 0, stream>>>(xnb, w_g + i * 65536, gbia + i * HD,
                                                            nullptr, gB, nullptr, nullptr,
                                                            nullptr, nullptr);
        // sequential recurrence
        scan_k<<<8, 64, 0, stream>>>(Amat + i * 4096, u, Hs);
        // y = Hs @ Cm^T + bias_C (bf16)
        gemm_k<SD, HD, 3><<<dim3(128, 4), 256, 0, stream>>>(Hs, w_c + i * 16384, bC + i * HD,
                                                            nullptr, yb, nullptr, nullptr,
                                                            nullptr, nullptr);
        // y2 = y @ proj_w^T + proj_b;  h += gate*y2 + (1-gate)*xn ; hb = bf16(h)
        gemm_k<HD, HD, 4><<<dim3(128, 4), 256, 0, stream>>>(yb, w_p + i * 65536, pb + i * HD,
                                                            h, hb, nullptr, nullptr, gB, xnb);
    }
    // out = h @ out_proj_w^T + out_proj_b
    gemm_k<HD, DOUT, 0><<<dim3(128, 12), 256, 0, stream>>>(hb, w_o, ob, (float*)d_out, nullptr,
                                                           nullptr, nullptr, nullptr, nullptr);
}

// Round 2
// 602.817 us; speedup vs baseline: 4.8105x; 4.8105x over previous
//
#include <hip/hip_runtime.h>

typedef float f32x4 __attribute__((ext_vector_type(4)));
typedef short short8 __attribute__((ext_vector_type(8)));

#define T_LEN 2048
#define NB 8
#define HD 256
#define SD 64
#define DIN 768
#define DOUT 768
#define NCHUNK 32
#define CLEN 64

__device__ __forceinline__ unsigned short f2bf(float f) {
    unsigned int u = __float_as_uint(f);
    unsigned int r = u + 0x7FFFu + ((u >> 16) & 1u);
    return (unsigned short)(r >> 16);
}
__device__ __forceinline__ float bf2f(unsigned short h) {
    return __uint_as_float(((unsigned int)h) << 16);
}

// ---------------- conversions ----------------
__global__ __launch_bounds__(256) void cvt_x_k(const float* __restrict__ s,
                                               unsigned short* __restrict__ d, int n4) {
    int i = blockIdx.x * 256 + threadIdx.x;
    if (i >= n4) return;
    float4 v = reinterpret_cast<const float4*>(s)[i];
    ushort4 o;
    o.x = f2bf(v.x); o.y = f2bf(v.y); o.z = f2bf(v.z); o.w = f2bf(v.w);
    reinterpret_cast<ushort4*>(d)[i] = o;
}

__global__ __launch_bounds__(256) void cvt_w_k(const float* __restrict__ s0, const float* __restrict__ s1,
                                               const float* __restrict__ s2, const float* __restrict__ s3,
                                               const float* __restrict__ s4, const float* __restrict__ s5,
                                               unsigned short* __restrict__ d) {
    int i = blockIdx.x * 256 + threadIdx.x;
    if (i >= 1048576) return;
    float v;
    if (i < 196608)      v = s0[i];
    else if (i < 262144) v = s1[i - 196608];
    else if (i < 524288) v = s2[i - 262144];
    else if (i < 786432) v = s3[i - 524288];
    else if (i < 851968) v = s4[i - 786432];
    else                 v = s5[i - 851968];
    d[i] = f2bf(v);
}

// ---------------- A^64 per layer: 6 in-place LDS squarings ----------------
__global__ __launch_bounds__(256) void matpow_k(const float* __restrict__ A, float* __restrict__ Apow) {
    __shared__ float M[64][65];
    const int l = blockIdx.x;
    const int tid = threadIdx.x;
    const float* src = A + l * 4096;
    for (int i = tid; i < 4096; i += 256) M[i >> 6][i & 63] = src[i];
    __syncthreads();
    const int r = tid >> 2, c0 = (tid & 3) << 4;
    for (int it = 0; it < 6; it++) {
        float acc[16];
#pragma unroll
        for (int j = 0; j < 16; j++) acc[j] = 0.f;
        for (int k = 0; k < 64; k++) {
            float av = M[r][k];
#pragma unroll
            for (int j = 0; j < 16; j++) acc[j] = fmaf(av, M[k][c0 + j], acc[j]);
        }
        __syncthreads();
#pragma unroll
        for (int j = 0; j < 16; j++) M[r][c0 + j] = acc[j];
        __syncthreads();
    }
    for (int i = tid; i < 4096; i += 256) Apow[l * 4096 + i] = M[i >> 6][i & 63];
}

// ---------------- LayerNorm: h fp32 -> xn bf16 ----------------
__global__ __launch_bounds__(256) void ln_k(const float* __restrict__ h, const float* __restrict__ g,
                                            const float* __restrict__ be, unsigned short* __restrict__ xnb) {
    int row = blockIdx.x * 4 + (threadIdx.x >> 6);
    int l = threadIdx.x & 63;
    const float4 x = *reinterpret_cast<const float4*>(h + row * HD + l * 4);
    float s = x.x + x.y + x.z + x.w;
    float s2 = x.x * x.x + x.y * x.y + x.z * x.z + x.w * x.w;
#pragma unroll
    for (int m = 1; m < 64; m <<= 1) { s += __shfl_xor(s, m); s2 += __shfl_xor(s2, m); }
    float mean = s * (1.f / 256.f);
    float var = s2 * (1.f / 256.f) - mean * mean;
    float rstd = rsqrtf(var + 1e-5f);
    int c = l * 4;
    ushort4 o;
    o.x = f2bf((x.x - mean) * rstd * g[c + 0] + be[c + 0]);
    o.y = f2bf((x.y - mean) * rstd * g[c + 1] + be[c + 1]);
    o.z = f2bf((x.z - mean) * rstd * g[c + 2] + be[c + 2]);
    o.w = f2bf((x.w - mean) * rstd * g[c + 3] + be[c + 3]);
    *reinterpret_cast<ushort4*>(xnb + row * HD + l * 4) = o;
}

// ---------------- GEMM with epilogue modes (unchanged from round 1) ----------------
template <int K, int N, int MODE>
__global__ __launch_bounds__(256) void gemm_k(const unsigned short* __restrict__ A,
                                              const unsigned short* __restrict__ W,
                                              const float* __restrict__ bias,
                                              float* __restrict__ outf, unsigned short* __restrict__ outb,
                                              const float* __restrict__ aux0, const float* __restrict__ aux1,
                                              const unsigned short* __restrict__ gb,
                                              const unsigned short* __restrict__ xnb) {
    const int l = threadIdx.x & 63, w = threadIdx.x >> 6;
    const int ll = l & 15, lh = l >> 4;
    const int m0 = blockIdx.x * 128 + w * 32;
    const int n0 = blockIdx.y * 64;
    f32x4 acc[2][4] = {};
    const unsigned short* Ap = A + (size_t)(m0 + ll) * K + lh * 8;
    const unsigned short* Wp = W + (size_t)(n0 + ll) * K + lh * 8;
#pragma unroll
    for (int k0 = 0; k0 < K; k0 += 32) {
        short8 a0 = *reinterpret_cast<const short8*>(Ap + k0);
        short8 a1 = *reinterpret_cast<const short8*>(Ap + 16 * K + k0);
        short8 b0 = *reinterpret_cast<const short8*>(Wp + k0);
        short8 b1 = *reinterpret_cast<const short8*>(Wp + 16 * K + k0);
        short8 b2 = *reinterpret_cast<const short8*>(Wp + 32 * K + k0);
        short8 b3 = *reinterpret_cast<const short8*>(Wp + 48 * K + k0);
        acc[0][0] = __builtin_amdgcn_mfma_f32_16x16x32_bf16(a0, b0, acc[0][0], 0, 0, 0);
        acc[0][1] = __builtin_amdgcn_mfma_f32_16x16x32_bf16(a0, b1, acc[0][1], 0, 0, 0);
        acc[0][2] = __builtin_amdgcn_mfma_f32_16x16x32_bf16(a0, b2, acc[0][2], 0, 0, 0);
        acc[0][3] = __builtin_amdgcn_mfma_f32_16x16x32_bf16(a0, b3, acc[0][3], 0, 0, 0);
        acc[1][0] = __builtin_amdgcn_mfma_f32_16x16x32_bf16(a1, b0, acc[1][0], 0, 0, 0);
        acc[1][1] = __builtin_amdgcn_mfma_f32_16x16x32_bf16(a1, b1, acc[1][1], 0, 0, 0);
        acc[1][2] = __builtin_amdgcn_mfma_f32_16x16x32_bf16(a1, b2, acc[1][2], 0, 0, 0);
        acc[1][3] = __builtin_amdgcn_mfma_f32_16x16x32_bf16(a1, b3, acc[1][3], 0, 0, 0);
    }
#pragma unroll
    for (int mf = 0; mf < 2; mf++)
#pragma unroll
        for (int nf = 0; nf < 4; nf++)
#pragma unroll
            for (int r = 0; r < 4; r++) {
                int m = m0 + mf * 16 + lh * 4 + r;
                int n = n0 + nf * 16 + ll;
                float v = acc[mf][nf][r] + bias[n];
                if constexpr (MODE == 0) {
                    outf[(size_t)m * N + n] = v;
                } else if constexpr (MODE == 1) {
                    float uu = aux0[n] * v + aux1[n];
                    int t = m & 2047, b = m >> 11;
                    outf[((t << 3) + b) * 64 + n] = uu;
                } else if constexpr (MODE == 2) {
                    float gg = 1.f / (1.f + __expf(-v));
                    outb[(size_t)m * N + n] = f2bf(gg);
                } else if constexpr (MODE == 3) {
                    outb[(size_t)m * N + n] = f2bf(v);
                } else if constexpr (MODE == 4) {
                    int t = m >> 3, b = m & 7;
                    int idx = ((b << 11) + t) * HD + n;
                    float g = bf2f(gb[idx]);
                    float xv = bf2f(xnb[idx]);
                    float hn = outf[idx] + g * v + (1.f - g) * xv;
                    outf[idx] = hn;
                    outb[idx] = f2bf(hn);
                }
            }
}

// ---------------- scan helpers ----------------
__device__ __forceinline__ void loadA64(const float* __restrict__ Af, int s, float* a) {
#pragma unroll
    for (int q = 0; q < 16; q++) {
        float4 v = reinterpret_cast<const float4*>(Af + s * 64)[q];
        a[q * 4 + 0] = v.x; a[q * 4 + 1] = v.y; a[q * 4 + 2] = v.z; a[q * 4 + 3] = v.w;
    }
}

// h_new = A @ h + uu  (lane s holds row s in a[], component s of h)
__device__ __forceinline__ float step64(const float* a, float h, float uu) {
    float ac0 = uu, ac1 = 0.f, ac2 = 0.f, ac3 = 0.f;
#pragma unroll
    for (int k = 0; k < 64; k += 4) {
        float b0 = __int_as_float(__builtin_amdgcn_readlane(__float_as_int(h), k + 0));
        float b1 = __int_as_float(__builtin_amdgcn_readlane(__float_as_int(h), k + 1));
        float b2 = __int_as_float(__builtin_amdgcn_readlane(__float_as_int(h), k + 2));
        float b3 = __int_as_float(__builtin_amdgcn_readlane(__float_as_int(h), k + 3));
        ac0 = fmaf(b0, a[k + 0], ac0);
        ac1 = fmaf(b1, a[k + 1], ac1);
        ac2 = fmaf(b2, a[k + 2], ac2);
        ac3 = fmaf(b3, a[k + 3], ac3);
    }
    return (ac0 + ac1) + (ac2 + ac3);
}

// pass 1: chunk-local linear scan from zero state -> final state per (chunk,batch)
__global__ __launch_bounds__(64) void scan_chunk_k(const float* __restrict__ Af,
                                                   const float* __restrict__ u,
                                                   float* __restrict__ Slast) {
    const int c = blockIdx.x >> 3, b = blockIdx.x & 7;
    const int s = threadIdx.x;
    float a[64];
    loadA64(Af, s, a);
    const float* up = u + (c * CLEN) * 512 + b * 64 + s;
    float h = 0.f;
    float un = up[0];
    for (int i = 0; i < CLEN; i++) {
        float uu = un;
        if (i < CLEN - 1) un = up[(i + 1) * 512];
        h = step64(a, h, uu);
    }
    Slast[blockIdx.x * 64 + s] = h;
}

// pass 2: sequential carry across chunks: carry[c+1] = A^64 @ carry[c] + Slast[c]
__global__ __launch_bounds__(64) void carry_k(const float* __restrict__ Apow,
                                              const float* __restrict__ Slast,
                                              float* __restrict__ Carry) {
    const int b = blockIdx.x;
    const int s = threadIdx.x;
    float a[64];
    loadA64(Apow, s, a);
    float carry = 0.f;
    float sl = Slast[b * 64 + s];
    for (int c = 0; c < NCHUNK; c++) {
        Carry[(c * 8 + b) * 64 + s] = carry;
        float sl_cur = sl;
        if (c < NCHUNK - 1) sl = Slast[((c + 1) * 8 + b) * 64 + s];
        carry = step64(a, carry, sl_cur);
    }
}

// pass 3: replay each chunk from true carry, emit bf16 states + overflow flag
__global__ __launch_bounds__(64) void replay_k(const float* __restrict__ Af,
                                               const float* __restrict__ u,
                                               const float* __restrict__ Carry,
                                               unsigned short* __restrict__ Hs,
                                               int* __restrict__ flag) {
    const int c = blockIdx.x >> 3, b = blockIdx.x & 7;
    const int s = threadIdx.x;
    float a[64];
    loadA64(Af, s, a);
    float h = Carry[blockIdx.x * 64 + s];
    const float* up = u + (c * CLEN) * 512 + b * 64 + s;
    unsigned short* hp = Hs + (c * CLEN) * 512 + b * 64 + s;
    bool bad = false;
    float un = up[0];
    for (int i = 0; i < CLEN; i++) {
        float uu = un;
        if (i < CLEN - 1) un = up[(i + 1) * 512];
        h = step64(a, h, uu);
        bad |= (fabsf(h) > 10.f);
        hp[i * 512] = f2bf(h);
    }
    if (__any(bad ? 1 : 0)) {
        if (s == 0) atomicOr(flag, 1);
    }
}

// pass 4: exact sequential fallback (runs only if speculation failed)
__global__ __launch_bounds__(64) void scan_seq_k(const float* __restrict__ Af,
                                                 const float* __restrict__ u,
                                                 unsigned short* __restrict__ Hs,
                                                 const int* __restrict__ flag) {
    if (*flag == 0) return;
    const int b = blockIdx.x;
    const int s = threadIdx.x;
    float a[64];
    loadA64(Af, s, a);
    float h = 0.f;
    for (int t = 0; t < T_LEN; t++) {
        float uu = u[((t << 3) + b) * 64 + s];
        float hp = step64(a, h, uu);
        h = fminf(fmaxf(hp, -10.f), 10.f);
        Hs[((t << 3) + b) * 64 + s] = f2bf(h);
    }
}

// ---------------- launch ----------------
extern "C" void kernel_launch(void* const* d_in, const int* in_sizes, int n_in,
                              void* d_out, int out_size, void* d_ws, size_t ws_size,
                              hipStream_t stream) {
    const float* x    = (const float*)d_in[0];
    const float* inw  = (const float*)d_in[1];
    const float* inb  = (const float*)d_in[2];
    const float* lng  = (const float*)d_in[3];
    const float* lnb  = (const float*)d_in[4];
    const float* ipw  = (const float*)d_in[5];
    const float* ipb  = (const float*)d_in[6];
    const float* Amat = (const float*)d_in[7];
    const float* Bv   = (const float*)d_in[8];
    const float* Cm   = (const float*)d_in[9];
    const float* bA   = (const float*)d_in[10];
    const float* bC   = (const float*)d_in[11];
    const float* gw   = (const float*)d_in[12];
    const float* gbia = (const float*)d_in[13];
    const float* pw   = (const float*)d_in[14];
    const float* pb   = (const float*)d_in[15];
    const float* ow   = (const float*)d_in[16];
    const float* ob   = (const float*)d_in[17];

    char* ws = (char*)d_ws;
    unsigned short* xb = (unsigned short*)(ws + 0);          // 25165824 B (region reused below)
    float*          u  = (float*)(ws + 0);                   // 4 MB
    unsigned short* Hs = (unsigned short*)(ws + 4194304);    // 2 MB
    unsigned short* yb = (unsigned short*)(ws + 6291456);    // 8 MB
    unsigned short* hb = (unsigned short*)(ws + 14680064);   // 8 MB
    unsigned short* wb = (unsigned short*)(ws + 25165824);   // 2 MB
    float*          h  = (float*)(ws + 27262976);            // 16 MB
    unsigned short* xnb = (unsigned short*)(ws + 44040192);  // 8 MB
    unsigned short* gB  = (unsigned short*)(ws + 52428800);  // 8 MB

    // small scan scratch lives in d_out (50 MB, fully overwritten by final GEMM)
    char* sc = (char*)d_out;
    float* Apow  = (float*)(sc + 0);        // 64 KB: [4][64][64]
    float* Slast = (float*)(sc + 65536);    // 64 KB: [32*8][64]
    float* Carry = (float*)(sc + 131072);   // 64 KB
    int*   flag  = (int*)(sc + 196608);     // 16 B: per-layer overflow flags

    const unsigned short* w_in = wb + 0;
    const unsigned short* w_ip = wb + 196608;
    const unsigned short* w_g  = wb + 262144;
    const unsigned short* w_p  = wb + 524288;
    const unsigned short* w_c  = wb + 786432;
    const unsigned short* w_o  = wb + 851968;

    hipMemsetAsync(flag, 0, 16, stream);
    cvt_x_k<<<12288, 256, 0, stream>>>(x, xb, 3145728);
    cvt_w_k<<<4096, 256, 0, stream>>>(inw, ipw, gw, pw, Cm, ow, wb);
    matpow_k<<<4, 256, 0, stream>>>(Amat, Apow);

    gemm_k<DIN, HD, 0><<<dim3(128, 4), 256, 0, stream>>>(xb, w_in, inb, h, nullptr,
                                                         nullptr, nullptr, nullptr, nullptr);
    for (int i = 0; i < 4; i++) {
        ln_k<<<4096, 256, 0, stream>>>(h, lng + i * HD, lnb + i * HD, xnb);
        gemm_k<HD, SD, 1><<<dim3(128, 1), 256, 0, stream>>>(xnb, w_ip + i * 16384, ipb + i * SD,
                                                            u, nullptr, Bv + i * SD, bA + i * SD,
                                                            nullptr, nullptr);
        gemm_k<HD, HD, 2><<<dim3(128, 4), 256, 0, stream>>>(xnb, w_g + i * 65536, gbia + i * HD,
                                                            nullptr, gB, nullptr, nullptr,
                                                            nullptr, nullptr);
        scan_chunk_k<<<256, 64, 0, stream>>>(Amat + i * 4096, u, Slast);
        carry_k<<<8, 64, 0, stream>>>(Apow + i * 4096, Slast, Carry);
        replay_k<<<256, 64, 0, stream>>>(Amat + i * 4096, u, Carry, Hs, flag + i);
        scan_seq_k<<<8, 64, 0, stream>>>(Amat + i * 4096, u, Hs, flag + i);
        gemm_k<SD, HD, 3><<<dim3(128, 4), 256, 0, stream>>>(Hs, w_c + i * 16384, bC + i * HD,
                                                            nullptr, yb, nullptr, nullptr,
                                                            nullptr, nullptr);
        gemm_k<HD, HD, 4><<<dim3(128, 4), 256, 0, stream>>>(yb, w_p + i * 65536, pb + i * HD,
                                                            h, hb, nullptr, nullptr, gB, xnb);
    }
    gemm_k<HD, DOUT, 0><<<dim3(128, 12), 256, 0, stream>>>(hb, w_o, ob, (float*)d_out, nullptr,
                                                           nullptr, nullptr, nullptr, nullptr);
}